// Round 1
// baseline (1221.807 us; speedup 1.0000x reference)
//
#include <hip/hip_runtime.h>
#include <math.h>

#define HIDN 512
#define PROJ 1024
#define ATTN 128
#define BATCH 4
#define SEQ 2048
#define N1 (2*PROJ+ATTN)      // 2176
#define ROWS (BATCH*SEQ)      // 8192

// tile params: 64x64 tile, BK=16, 256 threads (16x16), each thread 4x4
#define BM 64
#define BN 64
#define BKK 16

// ---------------- Kernel 1: gva = silu(node @ w1 + b1), scatter to gates/values/base
__global__ void k_gemm1(const float* __restrict__ A, const float* __restrict__ W,
                        const float* __restrict__ b1,
                        float* __restrict__ gates, float* __restrict__ values,
                        float* __restrict__ base)
{
    __shared__ float As[BKK][BM];
    __shared__ float Bs[BKK][BN];
    const int m0 = blockIdx.y * BM;
    const int n0 = blockIdx.x * BN;
    const int t = threadIdx.x;
    const int tx = t & 15, ty = t >> 4;
    float acc[4][4] = {};
    for (int k0 = 0; k0 < HIDN; k0 += BKK) {
        #pragma unroll
        for (int i = 0; i < 4; i++) {
            int lin = t + i*256;
            int m = lin >> 4, kk = lin & 15;
            As[kk][m] = A[(size_t)(m0+m)*HIDN + k0+kk];
        }
        #pragma unroll
        for (int i = 0; i < 4; i++) {
            int lin = t + i*256;
            int n = lin & 63, kk = lin >> 6;
            Bs[kk][n] = W[(size_t)(k0+kk)*N1 + n0+n];
        }
        __syncthreads();
        #pragma unroll
        for (int kk = 0; kk < BKK; kk++) {
            float am[4], bn[4];
            #pragma unroll
            for (int i=0;i<4;i++) am[i] = As[kk][ty*4+i];
            #pragma unroll
            for (int j=0;j<4;j++) bn[j] = Bs[kk][tx*4+j];
            #pragma unroll
            for (int i=0;i<4;i++)
                #pragma unroll
                for (int j=0;j<4;j++)
                    acc[i][j] += am[i]*bn[j];
        }
        __syncthreads();
    }
    #pragma unroll
    for (int i=0;i<4;i++) {
        int row = m0 + ty*4 + i;
        #pragma unroll
        for (int j=0;j<4;j++) {
            int col = n0 + tx*4 + j;
            float v = acc[i][j] + b1[col];
            v = v / (1.f + expf(-v));            // silu
            if (col < PROJ)        gates [(size_t)row*PROJ + col]          = v;
            else if (col < 2*PROJ) values[(size_t)row*PROJ + (col-PROJ)]   = v;
            else                   base  [(size_t)row*ATTN + (col-2*PROJ)] = v;
        }
    }
}

// ---------------- Kernel 2: qk affine + rope; q gets scaling folded in
__global__ void k_rope(const float* __restrict__ base, const float* __restrict__ msw,
                       const float* __restrict__ msb, const float* __restrict__ scaling,
                       float* __restrict__ q, float* __restrict__ k)
{
    int idx = blockIdx.x*blockDim.x + threadIdx.x;   // ROWS*64
    if (idx >= ROWS*64) return;
    int d = idx & 63;
    int row = idx >> 6;              // b*SEQ + l
    int l = row & (SEQ-1);
    float inv = powf(10000.f, -(float)d * (1.f/64.f));
    float ang = (float)l * inv;
    float s = sinf(ang), c = cosf(ang);
    const float* bp = base + (size_t)row*ATTN;
    float b_lo = bp[d], b_hi = bp[d+64];
    float x1q = b_lo*msw[d]      + msb[d];
    float x2q = b_hi*msw[d+64]   + msb[d+64];
    float x1k = b_lo*msw[128+d]    + msb[128+d];
    float x2k = b_hi*msw[128+d+64] + msb[128+d+64];
    float sc = scaling[0];
    q[(size_t)row*ATTN + d]    = (x1q*c - x2q*s)*sc;
    q[(size_t)row*ATTN + d+64] = (x2q*c + x1q*s)*sc;
    k[(size_t)row*ATTN + d]    = (x1k*c - x2k*s);
    k[(size_t)row*ATTN + d+64] = (x2k*c + x1k*s);
}

// ---------------- Kernel 3a: logits[b] = q[b] @ k[b]^T + bias[b]
__global__ void k_logits(const float* __restrict__ qg, const float* __restrict__ kg,
                         const float* __restrict__ bias, float* __restrict__ logits)
{
    __shared__ float As[BKK][BM];
    __shared__ float Bs[BKK][BN];
    const int b = blockIdx.z;
    const float* A  = qg + (size_t)b*SEQ*ATTN;
    const float* Kp = kg + (size_t)b*SEQ*ATTN;
    const int m0 = blockIdx.y * BM;
    const int n0 = blockIdx.x * BN;
    const int t = threadIdx.x;
    const int tx = t & 15, ty = t >> 4;
    float acc[4][4] = {};
    for (int k0 = 0; k0 < ATTN; k0 += BKK) {
        #pragma unroll
        for (int i = 0; i < 4; i++) {
            int lin = t + i*256;
            int m = lin >> 4, kk = lin & 15;
            As[kk][m] = A[(size_t)(m0+m)*ATTN + k0+kk];
        }
        #pragma unroll
        for (int i = 0; i < 4; i++) {
            int lin = t + i*256;
            int n = lin >> 4, kk = lin & 15;   // Bs[kk][n] = K[(n0+n)][k0+kk]
            Bs[kk][n] = Kp[(size_t)(n0+n)*ATTN + k0+kk];
        }
        __syncthreads();
        #pragma unroll
        for (int kk = 0; kk < BKK; kk++) {
            float am[4], bn[4];
            #pragma unroll
            for (int i=0;i<4;i++) am[i] = As[kk][ty*4+i];
            #pragma unroll
            for (int j=0;j<4;j++) bn[j] = Bs[kk][tx*4+j];
            #pragma unroll
            for (int i=0;i<4;i++)
                #pragma unroll
                for (int j=0;j<4;j++)
                    acc[i][j] += am[i]*bn[j];
        }
        __syncthreads();
    }
    const float* bb = bias + (size_t)b*SEQ*SEQ;
    float* lo = logits + (size_t)b*SEQ*SEQ;
    #pragma unroll
    for (int i=0;i<4;i++) {
        int row = m0 + ty*4 + i;
        #pragma unroll
        for (int j=0;j<4;j++) {
            int col = n0 + tx*4 + j;
            lo[(size_t)row*SEQ + col] = acc[i][j] + bb[(size_t)row*SEQ + col];
        }
    }
}

// ---------------- Kernel 3b: in-place row softmax over last dim (2048)
__inline__ __device__ float waveMax(float v){
    #pragma unroll
    for (int o=32;o>0;o>>=1) v = fmaxf(v, __shfl_xor(v,o,64));
    return v;
}
__inline__ __device__ float waveSum(float v){
    #pragma unroll
    for (int o=32;o>0;o>>=1) v += __shfl_xor(v,o,64);
    return v;
}
__global__ void k_softmax(float* __restrict__ logits)
{
    __shared__ float redm[4];
    __shared__ float reds[4];
    const int row = blockIdx.x;
    float* p = logits + (size_t)row*SEQ;
    const int t = threadIdx.x;       // 256
    const int wid = t >> 6, lane = t & 63;
    float v[8]; float m = -INFINITY;
    #pragma unroll
    for (int i=0;i<8;i++){ v[i] = p[t + i*256]; m = fmaxf(m, v[i]); }
    m = waveMax(m);
    if (lane==0) redm[wid] = m;
    __syncthreads();
    m = fmaxf(fmaxf(redm[0],redm[1]), fmaxf(redm[2],redm[3]));
    float s = 0.f;
    #pragma unroll
    for (int i=0;i<8;i++){ v[i] = expf(v[i]-m); s += v[i]; }
    s = waveSum(s);
    if (lane==0) reds[wid] = s;
    __syncthreads();
    s = reds[0]+reds[1]+reds[2]+reds[3];
    float inv = 1.f/s;
    #pragma unroll
    for (int i=0;i<8;i++) p[t + i*256] = v[i]*inv;
}

// ---------------- Kernel 3c: aout[b] = attn[b] @ values[b]
__global__ void k_pv(const float* __restrict__ attn, const float* __restrict__ values,
                     float* __restrict__ aout)
{
    __shared__ float As[BKK][BM];
    __shared__ float Bs[BKK][BN];
    const int b = blockIdx.z;
    const float* A = attn   + (size_t)b*SEQ*SEQ;
    const float* B = values + (size_t)b*SEQ*PROJ;
    float* C       = aout   + (size_t)b*SEQ*PROJ;
    const int m0 = blockIdx.y * BM;
    const int n0 = blockIdx.x * BN;
    const int t = threadIdx.x;
    const int tx = t & 15, ty = t >> 4;
    float acc[4][4] = {};
    for (int k0 = 0; k0 < SEQ; k0 += BKK) {
        #pragma unroll
        for (int i = 0; i < 4; i++) {
            int lin = t + i*256;
            int m = lin >> 4, kk = lin & 15;
            As[kk][m] = A[(size_t)(m0+m)*SEQ + k0+kk];
        }
        #pragma unroll
        for (int i = 0; i < 4; i++) {
            int lin = t + i*256;
            int n = lin & 63, kk = lin >> 6;
            Bs[kk][n] = B[(size_t)(k0+kk)*PROJ + n0+n];
        }
        __syncthreads();
        #pragma unroll
        for (int kk = 0; kk < BKK; kk++) {
            float am[4], bn[4];
            #pragma unroll
            for (int i=0;i<4;i++) am[i] = As[kk][ty*4+i];
            #pragma unroll
            for (int j=0;j<4;j++) bn[j] = Bs[kk][tx*4+j];
            #pragma unroll
            for (int i=0;i<4;i++)
                #pragma unroll
                for (int j=0;j<4;j++)
                    acc[i][j] += am[i]*bn[j];
        }
        __syncthreads();
    }
    #pragma unroll
    for (int i=0;i<4;i++) {
        int row = m0 + ty*4 + i;
        #pragma unroll
        for (int j=0;j<4;j++) {
            int col = n0 + tx*4 + j;
            C[(size_t)row*PROJ + col] = acc[i][j];
        }
    }
}

// ---------------- Kernel 4: out = (aout * gates) @ w2 + b2
__global__ void k_gemm2(const float* __restrict__ aout, const float* __restrict__ gates,
                        const float* __restrict__ W, const float* __restrict__ b2,
                        float* __restrict__ out)
{
    __shared__ float As[BKK][BM];
    __shared__ float Bs[BKK][BN];
    const int m0 = blockIdx.y * BM;
    const int n0 = blockIdx.x * BN;
    const int t = threadIdx.x;
    const int tx = t & 15, ty = t >> 4;
    float acc[4][4] = {};
    for (int k0 = 0; k0 < PROJ; k0 += BKK) {
        #pragma unroll
        for (int i = 0; i < 4; i++) {
            int lin = t + i*256;
            int m = lin >> 4, kk = lin & 15;
            size_t gi = (size_t)(m0+m)*PROJ + k0+kk;
            As[kk][m] = aout[gi] * gates[gi];
        }
        #pragma unroll
        for (int i = 0; i < 4; i++) {
            int lin = t + i*256;
            int n = lin & 63, kk = lin >> 6;
            Bs[kk][n] = W[(size_t)(k0+kk)*HIDN + n0+n];
        }
        __syncthreads();
        #pragma unroll
        for (int kk = 0; kk < BKK; kk++) {
            float am[4], bn[4];
            #pragma unroll
            for (int i=0;i<4;i++) am[i] = As[kk][ty*4+i];
            #pragma unroll
            for (int j=0;j<4;j++) bn[j] = Bs[kk][tx*4+j];
            #pragma unroll
            for (int i=0;i<4;i++)
                #pragma unroll
                for (int j=0;j<4;j++)
                    acc[i][j] += am[i]*bn[j];
        }
        __syncthreads();
    }
    #pragma unroll
    for (int i=0;i<4;i++) {
        int row = m0 + ty*4 + i;
        #pragma unroll
        for (int j=0;j<4;j++) {
            int col = n0 + tx*4 + j;
            out[(size_t)row*HIDN + col] = acc[i][j] + b2[col];
        }
    }
}

extern "C" void kernel_launch(void* const* d_in, const int* in_sizes, int n_in,
                              void* d_out, int out_size, void* d_ws, size_t ws_size,
                              hipStream_t stream) {
    const float* node    = (const float*)d_in[0];
    const float* bias    = (const float*)d_in[1];
    const float* scaling = (const float*)d_in[2];
    const float* w1      = (const float*)d_in[3];
    const float* b1      = (const float*)d_in[4];
    const float* msw     = (const float*)d_in[5];
    const float* msb     = (const float*)d_in[6];
    const float* w2      = (const float*)d_in[7];
    const float* b2      = (const float*)d_in[8];
    float* out = (float*)d_out;

    float* ws = (float*)d_ws;
    float* gates  = ws;                                   // ROWS*PROJ
    float* values = gates  + (size_t)ROWS*PROJ;           // ROWS*PROJ
    float* base   = values + (size_t)ROWS*PROJ;           // ROWS*ATTN
    float* qbuf   = base   + (size_t)ROWS*ATTN;           // ROWS*ATTN
    float* kbuf   = qbuf   + (size_t)ROWS*ATTN;           // ROWS*ATTN
    float* logits = kbuf   + (size_t)ROWS*ATTN;           // BATCH*SEQ*SEQ
    float* aout   = logits + (size_t)BATCH*SEQ*SEQ;       // ROWS*PROJ

    // 1) gva = silu(node@w1+b1) -> gates/values/base
    k_gemm1<<<dim3(N1/BN, ROWS/BM), 256, 0, stream>>>(node, w1, b1, gates, values, base);
    // 2) rope -> q (scaled), k
    k_rope<<<(ROWS*64)/256, 256, 0, stream>>>(base, msw, msb, scaling, qbuf, kbuf);
    // 3a) logits = q@k^T + bias
    k_logits<<<dim3(SEQ/BN, SEQ/BM, BATCH), 256, 0, stream>>>(qbuf, kbuf, bias, logits);
    // 3b) softmax rows
    k_softmax<<<ROWS, 256, 0, stream>>>(logits);
    // 3c) aout = attn @ values
    k_pv<<<dim3(PROJ/BN, SEQ/BM, BATCH), 256, 0, stream>>>(logits, values, aout);
    // 4) out = (aout*gates)@w2 + b2
    k_gemm2<<<dim3(HIDN/BN, ROWS/BM), 256, 0, stream>>>(aout, gates, w2, b2, out);
}

// Round 3
// 217.840 us; speedup vs baseline: 5.6087x; 5.6087x over previous
//
#include <hip/hip_runtime.h>
#include <math.h>

#define HIDN 512
#define PROJ 1024
#define ATTN 128
#define BATCH 4
#define SEQ 2048
#define N1 (2*PROJ+ATTN)      // 2176
#define ROWS (BATCH*SEQ)      // 8192

typedef __attribute__((ext_vector_type(4))) float f32x4;
typedef __attribute__((ext_vector_type(8))) short bf16x8;

// bf16 <-> f32 via bit ops (round-to-nearest-even), no header dependency
__device__ __forceinline__ short f2bf(float x){
    unsigned u = __builtin_bit_cast(unsigned, x);
    unsigned rounding = 0x7fffu + ((u >> 16) & 1u);
    u += rounding;
    return (short)(u >> 16);
}
__device__ __forceinline__ float bf2f(short s){
    unsigned u = ((unsigned)(unsigned short)s) << 16;
    return __builtin_bit_cast(float, u);
}

__device__ __forceinline__ void gload16(const void* g, void* l){
    __builtin_amdgcn_global_load_lds((const __attribute__((address_space(1))) void*)g,
                                     (__attribute__((address_space(3))) void*)l,
                                     16, 0, 0);
}

// ---------------- m97-style bt-GEMM tile: C[128x128] = A[M][K] @ BT[N][K]^T
// 256 threads (4 waves, 2x2), 16x16x32 bf16 MFMA, single-buffered LDS.
template<class Epi>
__device__ __forceinline__ void gemm_bt_tile(const short* __restrict__ A, int lda,
                                             const short* __restrict__ BT, int ldb,
                                             int m0, int n0, int K, Epi epi)
{
    __shared__ __align__(16) short lA[128*64];
    __shared__ __align__(16) short lB[128*64];
    const int t = threadIdx.x;
    const int lane = t & 63;
    const int w = t >> 6;
    const int wr = (w >> 1) * 64, wc = (w & 1) * 64;
    const int half = lane >> 4, l16 = lane & 15;

    f32x4 acc[4][4];
    #pragma unroll
    for (int i=0;i<4;i++)
        #pragma unroll
        for (int j=0;j<4;j++)
            acc[i][j] = (f32x4){0.f,0.f,0.f,0.f};

    for (int k0 = 0; k0 < K; k0 += 64) {
        #pragma unroll
        for (int i = 0; i < 4; i++) {
            int li = i*256 + t;
            int r = li >> 3, s = li & 7;
            gload16(A + (size_t)(m0+r)*lda + k0 + s*8, lA + li*8);
        }
        #pragma unroll
        for (int i = 0; i < 4; i++) {
            int li = i*256 + t;
            int r = li >> 3, s = li & 7;
            gload16(BT + (size_t)(n0+r)*ldb + k0 + s*8, lB + li*8);
        }
        __syncthreads();
        #pragma unroll
        for (int kk = 0; kk < 64; kk += 32) {
            bf16x8 af[4], bfr[4];
            #pragma unroll
            for (int i=0;i<4;i++)
                af[i] = *(const bf16x8*)(lA + (wr + i*16 + l16)*64 + kk + half*8);
            #pragma unroll
            for (int j=0;j<4;j++)
                bfr[j] = *(const bf16x8*)(lB + (wc + j*16 + l16)*64 + kk + half*8);
            #pragma unroll
            for (int i=0;i<4;i++)
                #pragma unroll
                for (int j=0;j<4;j++)
                    acc[i][j] = __builtin_amdgcn_mfma_f32_16x16x32_bf16(af[i], bfr[j], acc[i][j], 0, 0, 0);
        }
        __syncthreads();
    }
    // C/D layout: col = lane&15, row = (lane>>4)*4 + q   [m89/m91 verified]
    #pragma unroll
    for (int i=0;i<4;i++)
        #pragma unroll
        for (int j=0;j<4;j++)
            #pragma unroll
            for (int q=0;q<4;q++)
                epi(m0 + wr + i*16 + half*4 + q, n0 + wc + j*16 + l16, acc[i][j][q]);
}

// ---------------- helpers ----------------
__global__ void k_cast_node(const float* __restrict__ in, short* __restrict__ out){
    int idx = blockIdx.x*256 + threadIdx.x;     // 4 elems each
    const float4 v = ((const float4*)in)[idx];
    short4 o; o.x = f2bf(v.x); o.y = f2bf(v.y); o.z = f2bf(v.z); o.w = f2bf(v.w);
    ((short4*)out)[idx] = o;
}

// out[c][r] = bf16(in[r][c]);  in: f32 [R][C]
__global__ void k_transpose_cast(const float* __restrict__ in, short* __restrict__ out,
                                 int R, int C){
    __shared__ short tile[64][65];
    int r0 = blockIdx.y*64, c0 = blockIdx.x*64;
    int t = threadIdx.x;
    #pragma unroll
    for (int i=0;i<16;i++){
        int lin = i*256 + t; int r = lin>>6, c = lin&63;
        tile[r][c] = f2bf(in[(size_t)(r0+r)*C + c0+c]);
    }
    __syncthreads();
    #pragma unroll
    for (int i=0;i<16;i++){
        int lin = i*256 + t; int c = lin>>6, r = lin&63;
        out[(size_t)(c0+c)*R + r0+r] = tile[r][c];
    }
}

// per-batch transpose: VT[z][c][r] = values[z*SEQ + r][c]   (bf16)
__global__ void k_transpose_v(const short* __restrict__ values, short* __restrict__ VT){
    __shared__ short tile[64][65];
    int z = blockIdx.z;
    int c0 = blockIdx.x*64, r0 = blockIdx.y*64;
    int t = threadIdx.x;
    #pragma unroll
    for (int i=0;i<16;i++){
        int lin = i*256 + t; int r = lin>>6, c = lin&63;
        tile[r][c] = values[(size_t)(z*SEQ + r0+r)*PROJ + c0+c];
    }
    __syncthreads();
    #pragma unroll
    for (int i=0;i<16;i++){
        int lin = i*256 + t; int c = lin>>6, r = lin&63;
        VT[((size_t)z*PROJ + c0+c)*SEQ + r0+r] = tile[r][c];
    }
}

// ---------------- GEMM1: silu(node@w1+b1) -> gates/values/base (bf16)
__global__ __launch_bounds__(256) void k_mm1(const short* __restrict__ nodeb,
        const short* __restrict__ w1T, const float* __restrict__ b1,
        short* __restrict__ gates, short* __restrict__ values, short* __restrict__ baseb){
    int n0 = blockIdx.x*128, m0 = blockIdx.y*128;
    gemm_bt_tile(nodeb, HIDN, w1T, HIDN, m0, n0, HIDN,
        [=](int row, int col, float v){
            v += b1[col];
            v = v / (1.f + __expf(-v));
            short bv = f2bf(v);
            if (col < PROJ)        gates [(size_t)row*PROJ + col]        = bv;
            else if (col < 2*PROJ) values[(size_t)row*PROJ + col-PROJ]   = bv;
            else                   baseb [(size_t)row*ATTN + col-2*PROJ] = bv;
        });
}

// ---------------- RoPE: affine + rotate, q pre-scaled (bf16 in/out)
__global__ void k_rope2(const short* __restrict__ baseb, const float* __restrict__ msw,
                        const float* __restrict__ msb, const float* __restrict__ scaling,
                        short* __restrict__ qb, short* __restrict__ kb){
    int idx = blockIdx.x*256 + threadIdx.x;     // ROWS*64
    int d = idx & 63;
    int row = idx >> 6;
    int l = row & (SEQ-1);
    float inv = exp2f(-(float)d * (13.287712379549449f/64.f));   // 10000^(-d/64)
    float ang = (float)l * inv;
    float s = sinf(ang), c = cosf(ang);
    const short* bp = baseb + (size_t)row*ATTN;
    float b_lo = bf2f(bp[d]), b_hi = bf2f(bp[d+64]);
    float x1q = b_lo*msw[d]        + msb[d];
    float x2q = b_hi*msw[d+64]     + msb[d+64];
    float x1k = b_lo*msw[128+d]    + msb[128+d];
    float x2k = b_hi*msw[128+d+64] + msb[128+d+64];
    float sc = scaling[0];
    qb[(size_t)row*ATTN + d]    = f2bf((x1q*c - x2q*s)*sc);
    qb[(size_t)row*ATTN + d+64] = f2bf((x2q*c + x1q*s)*sc);
    kb[(size_t)row*ATTN + d]    = f2bf(x1k*c - x2k*s);
    kb[(size_t)row*ATTN + d+64] = f2bf(x2k*c + x1k*s);
}

// ---------------- QK^T + bias -> logits f32
__global__ __launch_bounds__(256) void k_qk(const short* __restrict__ qb,
        const short* __restrict__ kb, const float* __restrict__ bias,
        float* __restrict__ logits){
    int z = blockIdx.z;
    const short* A = qb + (size_t)z*SEQ*ATTN;
    const short* B = kb + (size_t)z*SEQ*ATTN;
    const float* bb = bias + (size_t)z*SEQ*SEQ;
    float* lo = logits + (size_t)z*SEQ*SEQ;
    int n0 = blockIdx.x*128, m0 = blockIdx.y*128;
    gemm_bt_tile(A, ATTN, B, ATTN, m0, n0, ATTN,
        [=](int r, int c, float v){
            lo[(size_t)r*SEQ + c] = v + bb[(size_t)r*SEQ + c];
        });
}

// ---------------- softmax rows (f32 in), write bf16 P IN PLACE over logits
__inline__ __device__ float waveMax(float v){
    #pragma unroll
    for (int o=32;o>0;o>>=1) v = fmaxf(v, __shfl_xor(v,o,64));
    return v;
}
__inline__ __device__ float waveSum(float v){
    #pragma unroll
    for (int o=32;o>0;o>>=1) v += __shfl_xor(v,o,64);
    return v;
}
__global__ void k_softmax(float* __restrict__ logits){
    __shared__ float redm[4];
    __shared__ float reds[4];
    const int row = blockIdx.x;
    float* p = logits + (size_t)row*SEQ;
    short* prow = (short*)p;                 // bf16 row overlays first half of f32 row
    const int t = threadIdx.x;               // 256
    const int wid = t >> 6, lane = t & 63;
    float v[8]; float m = -INFINITY;
    #pragma unroll
    for (int i=0;i<8;i++){ v[i] = p[t + i*256]; m = fmaxf(m, v[i]); }
    m = waveMax(m);
    if (lane==0) redm[wid] = m;
    __syncthreads();
    m = fmaxf(fmaxf(redm[0],redm[1]), fmaxf(redm[2],redm[3]));
    float s = 0.f;
    #pragma unroll
    for (int i=0;i<8;i++){ v[i] = __expf(v[i]-m); s += v[i]; }
    s = waveSum(s);
    if (lane==0) reds[wid] = s;
    __syncthreads();
    s = reds[0]+reds[1]+reds[2]+reds[3];
    float inv = 1.f/s;
    #pragma unroll
    for (int i=0;i<8;i++) prow[t + i*256] = f2bf(v[i]*inv);
}

// ---------------- PV: a2 = (P @ V) * gates  (bf16 out)
__global__ __launch_bounds__(256) void k_pv2(const short* __restrict__ P,
        const short* __restrict__ VT, const short* __restrict__ gates,
        short* __restrict__ a2){
    int z = blockIdx.z;
    const short* A = P  + (size_t)z*SEQ*(2*SEQ);   // lda = 4096 (bf16 row inside f32 row)
    const short* B = VT + (size_t)z*PROJ*SEQ;      // ldb = 2048
    int n0 = blockIdx.x*128, m0 = blockIdx.y*128;
    gemm_bt_tile(A, 2*SEQ, B, SEQ, m0, n0, SEQ,
        [=](int r, int c, float v){
            size_t gi = ((size_t)z*SEQ + r)*PROJ + c;
            a2[gi] = f2bf(v * bf2f(gates[gi]));
        });
}

// ---------------- GEMM2: out = a2 @ w2 + b2  (f32 out)
__global__ __launch_bounds__(256) void k_mm2(const short* __restrict__ a2,
        const short* __restrict__ w2T, const float* __restrict__ b2,
        float* __restrict__ out){
    int n0 = blockIdx.x*128, m0 = blockIdx.y*128;
    gemm_bt_tile(a2, PROJ, w2T, PROJ, m0, n0, PROJ,
        [=](int r, int c, float v){
            out[(size_t)r*HIDN + c] = v + b2[c];
        });
}

extern "C" void kernel_launch(void* const* d_in, const int* in_sizes, int n_in,
                              void* d_out, int out_size, void* d_ws, size_t ws_size,
                              hipStream_t stream) {
    const float* node    = (const float*)d_in[0];
    const float* bias    = (const float*)d_in[1];
    const float* scaling = (const float*)d_in[2];
    const float* w1      = (const float*)d_in[3];
    const float* b1      = (const float*)d_in[4];
    const float* msw     = (const float*)d_in[5];
    const float* msb     = (const float*)d_in[6];
    const float* w2      = (const float*)d_in[7];
    const float* b2      = (const float*)d_in[8];
    float* out = (float*)d_out;

    char* p = (char*)d_ws;
    auto alloc = [&](size_t bytes){ char* r = p; p += (bytes + 255) & ~(size_t)255; return r; };
    short* nodeb  = (short*)alloc((size_t)ROWS*HIDN*2);        // 8.4 MB
    short* w1T    = (short*)alloc((size_t)N1*HIDN*2);          // 2.2 MB
    short* w2T    = (short*)alloc((size_t)HIDN*PROJ*2);        // 1.0 MB
    short* gates  = (short*)alloc((size_t)ROWS*PROJ*2);        // 16.8 MB
    short* values = (short*)alloc((size_t)ROWS*PROJ*2);        // 16.8 MB
    short* VT     = (short*)alloc((size_t)BATCH*PROJ*SEQ*2);   // 16.8 MB
    short* baseb  = (short*)alloc((size_t)ROWS*ATTN*2);        // 2.1 MB
    short* qb     = (short*)alloc((size_t)ROWS*ATTN*2);        // 2.1 MB
    short* kb     = (short*)alloc((size_t)ROWS*ATTN*2);        // 2.1 MB
    float* logits = (float*)alloc((size_t)BATCH*SEQ*SEQ*4);    // 67.1 MB (P bf16 overlays)
    short* a2     = (short*)alloc((size_t)ROWS*PROJ*2);        // 16.8 MB

    // prep casts / transposes
    k_cast_node<<<ROWS*HIDN/1024, 256, 0, stream>>>(node, nodeb);
    k_transpose_cast<<<dim3(N1/64, HIDN/64), 256, 0, stream>>>(w1, w1T, HIDN, N1);
    k_transpose_cast<<<dim3(HIDN/64, PROJ/64), 256, 0, stream>>>(w2, w2T, PROJ, HIDN);
    // 1) gva = silu(node@w1+b1)
    k_mm1<<<dim3(N1/128, ROWS/128), 256, 0, stream>>>(nodeb, w1T, b1, gates, values, baseb);
    // transpose values for PV's B^T layout
    k_transpose_v<<<dim3(PROJ/64, SEQ/64, BATCH), 256, 0, stream>>>(values, VT);
    // 2) rope
    k_rope2<<<ROWS*64/256, 256, 0, stream>>>(baseb, msw, msb, scaling, qb, kb);
    // 3a) logits = q@k^T + bias
    k_qk<<<dim3(SEQ/128, SEQ/128, BATCH), 256, 0, stream>>>(qb, kb, bias, logits);
    // 3b) softmax -> bf16 P in place
    k_softmax<<<ROWS, 256, 0, stream>>>(logits);
    // 3c) a2 = (P@V)*gates
    k_pv2<<<dim3(PROJ/128, SEQ/128, BATCH), 256, 0, stream>>>((const short*)logits, VT, gates, a2);
    // 4) out = a2@w2 + b2
    k_mm2<<<dim3(HIDN/128, ROWS/128), 256, 0, stream>>>(a2, w2T, b2, out);
}